// Round 1
// baseline (10248.792 us; speedup 1.0000x reference)
//
#include <hip/hip_runtime.h>

#define EMB_DIM 64

// init: acc = x = concat(user, item); y = 0   (all as float4 lanes)
__global__ void lgcn_init(const float* __restrict__ user_w,
                          const float* __restrict__ item_w,
                          float* __restrict__ acc,
                          float* __restrict__ x,
                          float* __restrict__ y,
                          int user_n4, int n4) {
    int i = blockIdx.x * blockDim.x + threadIdx.x;
    if (i >= n4) return;
    float4 v;
    if (i < user_n4) v = ((const float4*)user_w)[i];
    else             v = ((const float4*)item_w)[i - user_n4];
    ((float4*)acc)[i] = v;
    ((float4*)x)[i]   = v;
    ((float4*)y)[i]   = make_float4(0.f, 0.f, 0.f, 0.f);
}

// SpMM: y[row] += val * x[col], 16 threads per edge, float4 per thread
__global__ void lgcn_spmm(const int* __restrict__ erow,
                          const int* __restrict__ ecol,
                          const float* __restrict__ eval_,
                          const float* __restrict__ x,
                          float* __restrict__ y,
                          int nnz) {
    long long t = (long long)blockIdx.x * blockDim.x + threadIdx.x;
    long long total = (long long)nnz * 16;
    if (t >= total) return;
    int e = (int)(t >> 4);
    int c = (int)(t & 15);
    int r  = erow[e];
    int cc = ecol[e];
    float v = eval_[e];
    float4 xv = ((const float4*)x)[(size_t)cc * 16 + c];
    float* yp = y + (size_t)r * EMB_DIM + c * 4;
    atomicAdd(yp + 0, v * xv.x);
    atomicAdd(yp + 1, v * xv.y);
    atomicAdd(yp + 2, v * xv.z);
    atomicAdd(yp + 3, v * xv.w);
}

// post: acc = (acc + y) * scale; optionally zero xold (becomes next y)
__global__ void lgcn_post(float* __restrict__ acc,
                          const float* __restrict__ y,
                          float* __restrict__ xold,
                          float scale, int zero_x, int n4) {
    int i = blockIdx.x * blockDim.x + threadIdx.x;
    if (i >= n4) return;
    float4 a = ((float4*)acc)[i];
    float4 b = ((const float4*)y)[i];
    a.x = (a.x + b.x) * scale;
    a.y = (a.y + b.y) * scale;
    a.z = (a.z + b.z) * scale;
    a.w = (a.w + b.w) * scale;
    ((float4*)acc)[i] = a;
    if (zero_x) ((float4*)xold)[i] = make_float4(0.f, 0.f, 0.f, 0.f);
}

extern "C" void kernel_launch(void* const* d_in, const int* in_sizes, int n_in,
                              void* d_out, int out_size, void* d_ws, size_t ws_size,
                              hipStream_t stream) {
    const float* user_w = (const float*)d_in[0];
    const float* item_w = (const float*)d_in[1];
    const int*   erow   = (const int*)d_in[2];
    const int*   ecol   = (const int*)d_in[3];
    const float* eval_  = (const float*)d_in[4];

    int n_users = in_sizes[0] / EMB_DIM;
    int n_items = in_sizes[1] / EMB_DIM;
    int n_total = n_users + n_items;
    int nnz     = in_sizes[2];

    float* acc  = (float*)d_out;
    float* bufA = (float*)d_ws;
    float* bufB = bufA + (size_t)n_total * EMB_DIM;

    int n4      = n_total * EMB_DIM / 4;
    int user_n4 = n_users * EMB_DIM / 4;

    lgcn_init<<<(n4 + 255) / 256, 256, 0, stream>>>(
        user_w, item_w, acc, bufA, bufB, user_n4, n4);

    float* x = bufA;
    float* y = bufB;
    for (int layer = 0; layer < 3; ++layer) {
        long long tot = (long long)nnz * 16;
        int blocks = (int)((tot + 255) / 256);
        lgcn_spmm<<<blocks, 256, 0, stream>>>(erow, ecol, eval_, x, y, nnz);
        const bool last = (layer == 2);
        lgcn_post<<<(n4 + 255) / 256, 256, 0, stream>>>(
            acc, y, x, last ? 0.25f : 1.0f, last ? 0 : 1, n4);
        float* t = x; x = y; y = t;
    }
}

// Round 2
// 1028.425 us; speedup vs baseline: 9.9655x; 9.9655x over previous
//
#include <hip/hip_runtime.h>

#define EMB_DIM 64
#define SCAN_T 256
#define SCAN_E 8
#define SCAN_CHUNK (SCAN_T * SCAN_E)   // 2048

// ---------- init: acc = x = concat(user, item) ----------
__global__ void lgcn_init(const float* __restrict__ user_w,
                          const float* __restrict__ item_w,
                          float* __restrict__ acc,
                          float* __restrict__ x,
                          int user_n4, int n4) {
    int i = blockIdx.x * blockDim.x + threadIdx.x;
    if (i >= n4) return;
    float4 v;
    if (i < user_n4) v = ((const float4*)user_w)[i];
    else             v = ((const float4*)item_w)[i - user_n4];
    ((float4*)acc)[i] = v;
    ((float4*)x)[i]   = v;
}

// ---------- CSR build ----------
__global__ void k_zero(int* __restrict__ p, int n) {
    int i = blockIdx.x * blockDim.x + threadIdx.x;
    if (i < n) p[i] = 0;
}

__global__ void k_hist(const int* __restrict__ erow, int* __restrict__ counts, int nnz) {
    int i = blockIdx.x * blockDim.x + threadIdx.x;
    if (i < nnz) atomicAdd(&counts[erow[i]], 1);
}

// pass1: per-block sums of counts
__global__ void k_scan1(const int* __restrict__ counts, int* __restrict__ bsum, int n) {
    __shared__ int s[SCAN_T];
    int base = blockIdx.x * SCAN_CHUNK;
    int t = threadIdx.x;
    int acc = 0;
    for (int k = 0; k < SCAN_E; ++k) {
        int idx = base + t * SCAN_E + k;
        if (idx < n) acc += counts[idx];
    }
    s[t] = acc;
    __syncthreads();
    for (int d = SCAN_T / 2; d > 0; d >>= 1) {
        if (t < d) s[t] += s[t + d];
        __syncthreads();
    }
    if (t == 0) bsum[blockIdx.x] = s[0];
}

// pass2: serial exclusive scan of block sums (nb ~ 74, trivial)
__global__ void k_scan2(const int* __restrict__ bsum, int* __restrict__ bscan, int nb) {
    if (threadIdx.x == 0 && blockIdx.x == 0) {
        int run = 0;
        for (int i = 0; i < nb; ++i) { bscan[i] = run; run += bsum[i]; }
    }
}

// pass3: block-local exclusive scan + block offset -> row_ptr, cursor
__global__ void k_scan3(const int* __restrict__ counts,
                        const int* __restrict__ bscan,
                        int* __restrict__ row_ptr,
                        int* __restrict__ cursor, int n) {
    __shared__ int s[SCAN_T];
    int base = blockIdx.x * SCAN_CHUNK;
    int t = threadIdx.x;
    int v[SCAN_E];
    int tot = 0;
    for (int k = 0; k < SCAN_E; ++k) {
        int idx = base + t * SCAN_E + k;
        v[k] = (idx < n) ? counts[idx] : 0;
        tot += v[k];
    }
    s[t] = tot;
    __syncthreads();
    // Hillis-Steele inclusive scan over thread totals
    for (int d = 1; d < SCAN_T; d <<= 1) {
        int add = (t >= d) ? s[t - d] : 0;
        __syncthreads();
        s[t] += add;
        __syncthreads();
    }
    int off = bscan[blockIdx.x] + s[t] - tot;  // exclusive prefix for this thread
    for (int k = 0; k < SCAN_E; ++k) {
        int idx = base + t * SCAN_E + k;
        if (idx < n) { row_ptr[idx] = off; cursor[idx] = off; }
        off += v[k];
    }
}

__global__ void k_scatter(const int* __restrict__ erow,
                          const int* __restrict__ ecol,
                          const float* __restrict__ eval_,
                          int* __restrict__ cursor,
                          int* __restrict__ scol,
                          float* __restrict__ sval, int nnz) {
    int i = blockIdx.x * blockDim.x + threadIdx.x;
    if (i >= nnz) return;
    int r = erow[i];
    int pos = atomicAdd(&cursor[r], 1);
    scol[pos] = ecol[i];
    sval[pos] = eval_[i];
}

// ---------- CSR SpMM: one wave per row, lane = dim; fused layer-accumulate ----------
__global__ void lgcn_spmm_csr(const int* __restrict__ row_ptr,
                              const int* __restrict__ row_end,
                              const int* __restrict__ scol,
                              const float* __restrict__ sval,
                              const float* __restrict__ x,
                              float* __restrict__ y,
                              float* __restrict__ out,
                              float scale, int is_last, int n) {
    int w = (blockIdx.x * blockDim.x + threadIdx.x) >> 6;
    int lane = threadIdx.x & 63;
    if (w >= n) return;
    int start = row_ptr[w];
    int end   = row_end[w];
    float acc = 0.f;
    int j = start;
    for (; j + 4 <= end; j += 4) {
        int c0 = scol[j], c1 = scol[j + 1], c2 = scol[j + 2], c3 = scol[j + 3];
        float v0 = sval[j], v1 = sval[j + 1], v2 = sval[j + 2], v3 = sval[j + 3];
        float x0 = x[(size_t)c0 * EMB_DIM + lane];
        float x1 = x[(size_t)c1 * EMB_DIM + lane];
        float x2 = x[(size_t)c2 * EMB_DIM + lane];
        float x3 = x[(size_t)c3 * EMB_DIM + lane];
        acc += v0 * x0 + v1 * x1 + v2 * x2 + v3 * x3;
    }
    for (; j < end; ++j)
        acc += sval[j] * x[(size_t)scol[j] * EMB_DIM + lane];
    size_t oi = (size_t)w * EMB_DIM + lane;
    y[oi] = acc;
    float a = out[oi] + acc;
    out[oi] = is_last ? a * scale : a;
}

extern "C" void kernel_launch(void* const* d_in, const int* in_sizes, int n_in,
                              void* d_out, int out_size, void* d_ws, size_t ws_size,
                              hipStream_t stream) {
    const float* user_w = (const float*)d_in[0];
    const float* item_w = (const float*)d_in[1];
    const int*   erow   = (const int*)d_in[2];
    const int*   ecol   = (const int*)d_in[3];
    const float* eval_  = (const float*)d_in[4];

    int n_users = in_sizes[0] / EMB_DIM;
    int n_items = in_sizes[1] / EMB_DIM;
    int n_total = n_users + n_items;
    int nnz     = in_sizes[2];

    // workspace layout
    char* ws = (char*)d_ws;
    float* x      = (float*)ws;                 ws += (size_t)n_total * EMB_DIM * 4;
    float* y      = (float*)ws;                 ws += (size_t)n_total * EMB_DIM * 4;
    int*   scol   = (int*)ws;                   ws += (size_t)nnz * 4;
    float* sval   = (float*)ws;                 ws += (size_t)nnz * 4;
    int*   counts = (int*)ws;                   ws += (size_t)n_total * 4;
    int*   row_ptr= (int*)ws;                   ws += (size_t)n_total * 4;
    int*   cursor = (int*)ws;                   ws += (size_t)n_total * 4;
    int*   bsum   = (int*)ws;                   ws += 4096;
    int*   bscan  = (int*)ws;                   ws += 4096;

    float* acc = (float*)d_out;
    int n4      = n_total * EMB_DIM / 4;
    int user_n4 = n_users * EMB_DIM / 4;

    lgcn_init<<<(n4 + 255) / 256, 256, 0, stream>>>(user_w, item_w, acc, x, user_n4, n4);

    // CSR build
    int nb = (n_total + SCAN_CHUNK - 1) / SCAN_CHUNK;
    k_zero<<<(n_total + 255) / 256, 256, 0, stream>>>(counts, n_total);
    k_hist<<<(nnz + 255) / 256, 256, 0, stream>>>(erow, counts, nnz);
    k_scan1<<<nb, SCAN_T, 0, stream>>>(counts, bsum, n_total);
    k_scan2<<<1, 64, 0, stream>>>(bsum, bscan, nb);
    k_scan3<<<nb, SCAN_T, 0, stream>>>(counts, bscan, row_ptr, cursor, n_total);
    k_scatter<<<(nnz + 255) / 256, 256, 0, stream>>>(erow, ecol, eval_, cursor, scol, sval, nnz);
    // after scatter, cursor[r] == row end

    // 3 propagation layers, ping-pong x/y, accumulate into d_out
    float* xin = x;
    float* yout = y;
    int waves_per_block = 256 / 64;
    int blocks = (n_total + waves_per_block - 1) / waves_per_block;
    for (int layer = 0; layer < 3; ++layer) {
        const bool last = (layer == 2);
        lgcn_spmm_csr<<<blocks, 256, 0, stream>>>(
            row_ptr, cursor, scol, sval, xin, yout, acc,
            0.25f, last ? 1 : 0, n_total);
        float* t = xin; xin = yout; yout = t;
    }
}